// Round 2
// baseline (153.313 us; speedup 1.0000x reference)
//
#include <hip/hip_runtime.h>
#include <hip/hip_bf16.h>
#include <math.h>

#define SEQ 16384
#define D   1024
#define NBLK_DOT 2048   // blocks in dot kernel; 1024 per head
#define WAVES_PER_BLK 4

// ---------------------------------------------------------------------------
// Kernel 1: logits + per-block softmax partials.
// Each wave: 4 consecutive rows (all in one head since 16 rows/block and
// 16384 % 16 == 0). 4 independent accumulators -> up to 16 float4 loads in
// flight. Butterfly-reduce, lane 0 stores 4 logits as float4.
// Then block-level partial max m_b and s_b = sum exp(x - m_b) over 16 rows.
// Blocks 0..1023 -> head 0, 1024..2047 -> head 1.
// ---------------------------------------------------------------------------
__global__ __launch_bounds__(256) void dot_partial_kernel(
    const float* __restrict__ g1, const float* __restrict__ g2,
    const float* __restrict__ wp1, const float* __restrict__ wp2,
    float* __restrict__ logits,
    float* __restrict__ blk_m, float* __restrict__ blk_s) {
  const int lane = threadIdx.x & 63;
  const int wid  = threadIdx.x >> 6;                 // 0..3
  const int w    = blockIdx.x * WAVES_PER_BLK + wid; // 0..8191
  const int r0   = w * 4;                            // first of 4 rows (global)
  const bool head1 = (r0 >= SEQ);
  const float* g  = head1 ? g2 : g1;
  const float* wp = head1 ? wp2 : wp1;
  const int row0  = head1 ? (r0 - SEQ) : r0;

  const float4* wpv = (const float4*)wp;
  float4 wv[4];
#pragma unroll
  for (int k = 0; k < 4; ++k) wv[k] = wpv[lane + 64 * k];

  const float4* rv = (const float4*)(g + (size_t)row0 * D);  // 256 float4/row
  float acc0 = 0.f, acc1 = 0.f, acc2 = 0.f, acc3 = 0.f;
#pragma unroll
  for (int k = 0; k < 4; ++k) {
    const int o = lane + 64 * k;
    float4 a0 = rv[o];
    float4 a1 = rv[o + 256];
    float4 a2 = rv[o + 512];
    float4 a3 = rv[o + 768];
    float4 wk = wv[k];
    acc0 = fmaf(a0.x, wk.x, fmaf(a0.y, wk.y, fmaf(a0.z, wk.z, fmaf(a0.w, wk.w, acc0))));
    acc1 = fmaf(a1.x, wk.x, fmaf(a1.y, wk.y, fmaf(a1.z, wk.z, fmaf(a1.w, wk.w, acc1))));
    acc2 = fmaf(a2.x, wk.x, fmaf(a2.y, wk.y, fmaf(a2.z, wk.z, fmaf(a2.w, wk.w, acc2))));
    acc3 = fmaf(a3.x, wk.x, fmaf(a3.y, wk.y, fmaf(a3.z, wk.z, fmaf(a3.w, wk.w, acc3))));
  }
#pragma unroll
  for (int off = 32; off > 0; off >>= 1) {
    acc0 += __shfl_xor(acc0, off, 64);
    acc1 += __shfl_xor(acc1, off, 64);
    acc2 += __shfl_xor(acc2, off, 64);
    acc3 += __shfl_xor(acc3, off, 64);
  }
  if (lane == 0) {
    *(float4*)(logits + r0) = make_float4(acc0, acc1, acc2, acc3);
  }

  // per-wave softmax partial (all lanes hold full sums)
  float mw = fmaxf(fmaxf(acc0, acc1), fmaxf(acc2, acc3));
  float sw = __expf(acc0 - mw) + __expf(acc1 - mw) +
             __expf(acc2 - mw) + __expf(acc3 - mw);

  __shared__ float lm[WAVES_PER_BLK], ls[WAVES_PER_BLK];
  if (lane == 0) { lm[wid] = mw; ls[wid] = sw; }
  __syncthreads();
  if (threadIdx.x == 0) {
    float M = fmaxf(fmaxf(lm[0], lm[1]), fmaxf(lm[2], lm[3]));
    float S = ls[0] * __expf(lm[0] - M) + ls[1] * __expf(lm[1] - M) +
              ls[2] * __expf(lm[2] - M) + ls[3] * __expf(lm[3] - M);
    blk_m[blockIdx.x] = M;
    blk_s[blockIdx.x] = S;
  }
}

// ---------------------------------------------------------------------------
// Kernel 2: reduce 1024 block-partials per head -> M, invS. One block/head.
// ---------------------------------------------------------------------------
__global__ __launch_bounds__(1024) void stats_kernel(
    const float* __restrict__ blk_m, const float* __restrict__ blk_s,
    float* __restrict__ stats) {
  const int h    = blockIdx.x;
  const int tid  = threadIdx.x;
  const int lane = tid & 63;
  const int wid  = tid >> 6;  // 16 waves

  float m = blk_m[h * 1024 + tid];
  float s = blk_s[h * 1024 + tid];

  __shared__ float sm[16], ssum[16];

  float mm = m;
#pragma unroll
  for (int off = 32; off > 0; off >>= 1)
    mm = fmaxf(mm, __shfl_xor(mm, off, 64));
  if (lane == 0) sm[wid] = mm;
  __syncthreads();
  float M = sm[0];
#pragma unroll
  for (int i = 1; i < 16; ++i) M = fmaxf(M, sm[i]);

  float c = s * __expf(m - M);
#pragma unroll
  for (int off = 32; off > 0; off >>= 1)
    c += __shfl_xor(c, off, 64);
  if (lane == 0) ssum[wid] = c;
  __syncthreads();
  if (tid == 0) {
    float S = 0.f;
#pragma unroll
    for (int i = 0; i < 16; ++i) S += ssum[i];
    stats[2 * h]     = M;
    stats[2 * h + 1] = 1.0f / S;
  }
}

// ---------------------------------------------------------------------------
// Kernel 3: out[i] = exp(logit[i] - M_h) * invS_h, vectorized float4.
// 8192 float4 total; 4096 per head (head = idx4 >> 12).
// ---------------------------------------------------------------------------
__global__ __launch_bounds__(256) void normalize_kernel(
    const float4* __restrict__ logits4, const float* __restrict__ stats,
    float4* __restrict__ out4) {
  const int i = blockIdx.x * blockDim.x + threadIdx.x;  // 0..8191
  const int h = i >> 12;
  const float M    = stats[2 * h];
  const float invS = stats[2 * h + 1];
  float4 v = logits4[i];
  float4 o;
  o.x = __expf(v.x - M) * invS;
  o.y = __expf(v.y - M) * invS;
  o.z = __expf(v.z - M) * invS;
  o.w = __expf(v.w - M) * invS;
  out4[i] = o;
}

extern "C" void kernel_launch(void* const* d_in, const int* in_sizes, int n_in,
                              void* d_out, int out_size, void* d_ws, size_t ws_size,
                              hipStream_t stream) {
  const float* g1  = (const float*)d_in[0];
  const float* g2  = (const float*)d_in[1];
  const float* wp1 = (const float*)d_in[2];
  const float* wp2 = (const float*)d_in[3];
  float* out = (float*)d_out;

  // workspace layout
  float* logits = (float*)d_ws;                  // 32768 floats
  float* blk_m  = logits + 2 * SEQ;              // 2048
  float* blk_s  = blk_m + NBLK_DOT;              // 2048
  float* stats  = blk_s + NBLK_DOT;              // 4 (M0, invS0, M1, invS1)

  dot_partial_kernel<<<NBLK_DOT, 256, 0, stream>>>(g1, g2, wp1, wp2,
                                                   logits, blk_m, blk_s);
  stats_kernel<<<2, 1024, 0, stream>>>(blk_m, blk_s, stats);
  normalize_kernel<<<32, 256, 0, stream>>>((const float4*)logits, stats,
                                           (float4*)out);
}

// Round 4
// 141.904 us; speedup vs baseline: 1.0804x; 1.0804x over previous
//
#include <hip/hip_runtime.h>
#include <hip/hip_bf16.h>
#include <math.h>

#define SEQ 16384
#define D   1024
#define NBLK_DOT 4096   // 4 waves/block, 2 rows/wave -> 8 rows/block
#define ROWS_PER_WAVE 2

typedef float floatx4 __attribute__((ext_vector_type(4)));

__device__ __forceinline__ floatx4 nt_load4(const float* p) {
  return __builtin_nontemporal_load((const floatx4*)p);
}

// ---------------------------------------------------------------------------
// Kernel 1: logits + per-block softmax partials.
// 4096 blocks x 256 thr = 16384 waves = 2 resident generations (block
// turnover keeps load issue flowing while earlier waves drain).
// Each wave: 2 consecutive rows, 8 independent dwordx4 nontemporal loads
// issued together. Blocks 0..2047 -> head 0, 2048..4095 -> head 1.
// ---------------------------------------------------------------------------
__global__ void dot_partial_kernel(
    const float* __restrict__ g1, const float* __restrict__ g2,
    const float* __restrict__ wp1, const float* __restrict__ wp2,
    float* __restrict__ logits,
    float* __restrict__ blk_m, float* __restrict__ blk_s) {
  const int lane = threadIdx.x & 63;
  const int wid  = threadIdx.x >> 6;                    // 0..3
  const int w    = blockIdx.x * 4 + wid;                // 0..16383
  const int r0   = w * ROWS_PER_WAVE;                   // global row pair
  const bool head1 = (blockIdx.x >= NBLK_DOT / 2);
  const float* g  = head1 ? g2 : g1;
  const float* wp = head1 ? wp2 : wp1;
  const int row0  = head1 ? (r0 - SEQ) : r0;

  floatx4 wv[4];
#pragma unroll
  for (int k = 0; k < 4; ++k)
    wv[k] = *((const floatx4*)wp + lane + 64 * k);

  const float* row = g + (size_t)row0 * D;

  // Issue all 8 loads before any FMA (independent, nontemporal).
  floatx4 a0 = nt_load4(row + 4 * (lane));
  floatx4 a1 = nt_load4(row + 4 * (lane + 64));
  floatx4 a2 = nt_load4(row + 4 * (lane + 128));
  floatx4 a3 = nt_load4(row + 4 * (lane + 192));
  floatx4 b0 = nt_load4(row + D + 4 * (lane));
  floatx4 b1 = nt_load4(row + D + 4 * (lane + 64));
  floatx4 b2 = nt_load4(row + D + 4 * (lane + 128));
  floatx4 b3 = nt_load4(row + D + 4 * (lane + 192));

  float acc0 = 0.f, acc1 = 0.f;
#pragma unroll
  for (int e = 0; e < 4; ++e) {
    acc0 = fmaf(a0[e], wv[0][e], acc0);
    acc0 = fmaf(a1[e], wv[1][e], acc0);
    acc0 = fmaf(a2[e], wv[2][e], acc0);
    acc0 = fmaf(a3[e], wv[3][e], acc0);
    acc1 = fmaf(b0[e], wv[0][e], acc1);
    acc1 = fmaf(b1[e], wv[1][e], acc1);
    acc1 = fmaf(b2[e], wv[2][e], acc1);
    acc1 = fmaf(b3[e], wv[3][e], acc1);
  }

#pragma unroll
  for (int off = 32; off > 0; off >>= 1) {
    acc0 += __shfl_xor(acc0, off, 64);
    acc1 += __shfl_xor(acc1, off, 64);
  }
  if (lane == 0) {
    *(float2*)(logits + r0) = make_float2(acc0, acc1);
  }

  // per-wave softmax partial
  float mw = fmaxf(acc0, acc1);
  float sw = __expf(acc0 - mw) + __expf(acc1 - mw);

  __shared__ float lm[4], ls[4];
  if (lane == 0) { lm[wid] = mw; ls[wid] = sw; }
  __syncthreads();
  if (threadIdx.x == 0) {
    float M = fmaxf(fmaxf(lm[0], lm[1]), fmaxf(lm[2], lm[3]));
    float S = ls[0] * __expf(lm[0] - M) + ls[1] * __expf(lm[1] - M) +
              ls[2] * __expf(lm[2] - M) + ls[3] * __expf(lm[3] - M);
    blk_m[blockIdx.x] = M;
    blk_s[blockIdx.x] = S;
  }
}

// ---------------------------------------------------------------------------
// Kernel 2: fused stats + normalize. 32 blocks x 256 threads.
// Blocks 0..15 -> head 0, 16..31 -> head 1. Each block redundantly reduces
// its head's 2048 (m,s) partials (16 KB, L2/L3-hot), then normalizes its
// 256-float4 slice of the output.
// ---------------------------------------------------------------------------
__global__ __launch_bounds__(256) void finalize_kernel(
    const float* __restrict__ blk_m, const float* __restrict__ blk_s,
    const float4* __restrict__ logits4, float4* __restrict__ out4) {
  const int head = blockIdx.x >> 4;          // 16 blocks per head
  const int tid  = threadIdx.x;
  const int lane = tid & 63;
  const int wid  = tid >> 6;

  // --- reduce 2048 partials: 8 per thread ---
  const float* pm = blk_m + head * (NBLK_DOT / 2) + tid * 8;
  const float* ps = blk_s + head * (NBLK_DOT / 2) + tid * 8;
  float M = -INFINITY, S = 0.f;
#pragma unroll
  for (int i = 0; i < 8; ++i) {
    float m = pm[i], s = ps[i];
    float nm = fmaxf(M, m);
    S = S * __expf(M - nm) + s * __expf(m - nm);
    M = nm;
  }
#pragma unroll
  for (int off = 32; off > 0; off >>= 1) {
    float m2 = __shfl_xor(M, off, 64);
    float s2 = __shfl_xor(S, off, 64);
    float nm = fmaxf(M, m2);
    S = S * __expf(M - nm) + s2 * __expf(m2 - nm);
    M = nm;
  }
  __shared__ float sm[4], ss[4], fin[2];
  if (lane == 0) { sm[wid] = M; ss[wid] = S; }
  __syncthreads();
  if (tid == 0) {
    float Mg = -INFINITY, Sg = 0.f;
#pragma unroll
    for (int i = 0; i < 4; ++i) {
      float nm = fmaxf(Mg, sm[i]);
      Sg = Sg * __expf(Mg - nm) + ss[i] * __expf(sm[i] - nm);
      Mg = nm;
    }
    fin[0] = Mg;
    fin[1] = 1.0f / Sg;
  }
  __syncthreads();
  const float Mg   = fin[0];
  const float invS = fin[1];

  // --- normalize this block's slice: 256 float4 ---
  const int i = head * 4096 + (blockIdx.x & 15) * 256 + tid;
  float4 v = logits4[i];
  float4 o;
  o.x = __expf(v.x - Mg) * invS;
  o.y = __expf(v.y - Mg) * invS;
  o.z = __expf(v.z - Mg) * invS;
  o.w = __expf(v.w - Mg) * invS;
  out4[i] = o;
}

extern "C" void kernel_launch(void* const* d_in, const int* in_sizes, int n_in,
                              void* d_out, int out_size, void* d_ws, size_t ws_size,
                              hipStream_t stream) {
  const float* g1  = (const float*)d_in[0];
  const float* g2  = (const float*)d_in[1];
  const float* wp1 = (const float*)d_in[2];
  const float* wp2 = (const float*)d_in[3];
  float* out = (float*)d_out;

  float* logits = (float*)d_ws;              // 32768 floats
  float* blk_m  = logits + 2 * SEQ;          // 4096
  float* blk_s  = blk_m + NBLK_DOT;          // 4096

  dot_partial_kernel<<<NBLK_DOT, 256, 0, stream>>>(g1, g2, wp1, wp2,
                                                   logits, blk_m, blk_s);
  finalize_kernel<<<32, 256, 0, stream>>>(blk_m, blk_s,
                                          (const float4*)logits, (float4*)out);
}